// Round 2
// baseline (576.077 us; speedup 1.0000x reference)
//
#include <hip/hip_runtime.h>

typedef __bf16 bf16_t;
typedef __bf16 bf16x8 __attribute__((ext_vector_type(8)));
typedef __bf16 bf16x4 __attribute__((ext_vector_type(4)));
typedef float f32x4 __attribute__((ext_vector_type(4)));

typedef const __attribute__((address_space(1))) void gv_t;
typedef __attribute__((address_space(3))) void lv_t;

#define NROWS 32768

__device__ __forceinline__ float wave_sum(float v) {
#pragma unroll
  for (int o = 32; o > 0; o >>= 1) v += __shfl_xor(v, o, 64);
  return v;
}

// ---------------- GEMM: C[M,N] = A[M,K] @ B[K,N] ----------------
// BT stored [N][K] bf16 (transposed weights). A is bf16 [M][K] unless CONVA
// (then fp32, converted during staging). EPI 0: relu(acc+bias)->bf16,
// EPI 1: acc+bias->f32 (bias may be nullptr).
template <int EPI, bool CONVA>
__global__ __launch_bounds__(256) void gemm_k(
    const void* __restrict__ Ap, const bf16_t* __restrict__ BT,
    const float* __restrict__ bias, void* __restrict__ Cp,
    const int M, const int N, const int K) {
  __shared__ bf16_t sA[128 * 32];
  __shared__ bf16_t sB[128 * 32];
  const int tid = threadIdx.x;
  const int lane = tid & 63;
  const int wid = tid >> 6;
  const int wr = wid >> 1;
  const int wc = wid & 1;
  const int bm0 = blockIdx.y * 128;
  const int bn0 = blockIdx.x * 128;

  f32x4 acc[4][4];
#pragma unroll
  for (int m = 0; m < 4; ++m)
#pragma unroll
    for (int n = 0; n < 4; ++n) acc[m][n] = f32x4{0.f, 0.f, 0.f, 0.f};

  auto stage = [&](int k0) {
    if constexpr (CONVA) {
      const float* Af = (const float*)Ap;
      const int rb = tid >> 3;
      const int ks = (tid & 7) << 2;
#pragma unroll
      for (int p = 0; p < 4; ++p) {
        const int row = rb + (p << 5);
        const float4 f = *(const float4*)(Af + (size_t)(bm0 + row) * K + k0 + ks);
        bf16x4 w;
        w[0] = (bf16_t)f.x; w[1] = (bf16_t)f.y;
        w[2] = (bf16_t)f.z; w[3] = (bf16_t)f.w;
        *(bf16x4*)(&sA[row * 32 + ks]) = w;
      }
    } else {
      const bf16_t* Ab = (const bf16_t*)Ap;
#pragma unroll
      for (int i = 0; i < 2; ++i) {
        const int off = wid * 2048 + i * 1024;
        const int lidx = off + lane * 16;
        const int row = lidx >> 6;
        const int kb = lidx & 63;
        gv_t* src = (gv_t*)((const char*)(Ab + (size_t)(bm0 + row) * K + k0) + kb);
        __builtin_amdgcn_global_load_lds(src, (lv_t*)((char*)sA + off), 16, 0, 0);
      }
    }
#pragma unroll
    for (int i = 0; i < 2; ++i) {
      const int off = wid * 2048 + i * 1024;
      const int lidx = off + lane * 16;
      const int col = lidx >> 6;
      const int kb = lidx & 63;
      gv_t* src = (gv_t*)((const char*)(BT + (size_t)(bn0 + col) * K + k0) + kb);
      __builtin_amdgcn_global_load_lds(src, (lv_t*)((char*)sB + off), 16, 0, 0);
    }
  };

  stage(0);
  const int arow = lane & 15;
  const int koff = (lane >> 4) * 8;
  for (int k0 = 0;;) {
    __syncthreads();  // staged data visible (drains vmcnt/lgkmcnt)
    bf16x8 af[4], bg[4];
#pragma unroll
    for (int m = 0; m < 4; ++m)
      af[m] = *(const bf16x8*)&sA[(wr * 64 + m * 16 + arow) * 32 + koff];
#pragma unroll
    for (int n = 0; n < 4; ++n)
      bg[n] = *(const bf16x8*)&sB[(wc * 64 + n * 16 + arow) * 32 + koff];
#pragma unroll
    for (int m = 0; m < 4; ++m)
#pragma unroll
      for (int n = 0; n < 4; ++n)
        acc[m][n] = __builtin_amdgcn_mfma_f32_16x16x32_bf16(af[m], bg[n], acc[m][n], 0, 0, 0);
    k0 += 32;
    if (k0 >= K) break;
    __syncthreads();  // reads done before restage
    stage(k0);
  }

  // epilogue: C layout col=lane&15, row=(lane>>4)*4+reg (m89/m91 verified)
  const int r0 = bm0 + wr * 64 + ((lane >> 4) << 2);
  const int c0 = bn0 + wc * 64 + (lane & 15);
  float bv[4];
#pragma unroll
  for (int n = 0; n < 4; ++n) bv[n] = bias ? bias[c0 + n * 16] : 0.f;
  if constexpr (EPI == 0) {
    bf16_t* C = (bf16_t*)Cp;
#pragma unroll
    for (int m = 0; m < 4; ++m)
#pragma unroll
      for (int n = 0; n < 4; ++n) {
        const size_t base = (size_t)(r0 + m * 16) * N + (c0 + n * 16);
#pragma unroll
        for (int r = 0; r < 4; ++r) {
          float v = acc[m][n][r] + bv[n];
          v = fmaxf(v, 0.f);
          C[base + (size_t)r * N] = (bf16_t)v;
        }
      }
  } else {
    float* C = (float*)Cp;
#pragma unroll
    for (int m = 0; m < 4; ++m)
#pragma unroll
      for (int n = 0; n < 4; ++n) {
        const size_t base = (size_t)(r0 + m * 16) * N + (c0 + n * 16);
#pragma unroll
        for (int r = 0; r < 4; ++r) {
          C[base + (size_t)r * N] = acc[m][n][r] + bv[n];
        }
      }
  }
}

// -------- setup: conn abs-sum + weight transpose/convert to bf16 --------
__global__ __launch_bounds__(256) void setup_k(
    const float* __restrict__ conn, float* __restrict__ accum,
    const float* __restrict__ W1, bf16_t* __restrict__ W1T,
    const float* __restrict__ W2, bf16_t* __restrict__ W2T,
    const float* __restrict__ metric, bf16_t* __restrict__ MT,
    const float* __restrict__ W3, bf16_t* __restrict__ W3T,
    const float* __restrict__ W4, bf16_t* __restrict__ W4T) {
  const int b = blockIdx.x, tid = threadIdx.x;
  __shared__ float sw[4];
  if (b < 512) {
    const float4* src = (const float4*)conn + (size_t)b * 8192;
    float s = 0.f;
    for (int i = tid; i < 8192; i += 256) {
      float4 v = src[i];
      s += fabsf(v.x) + fabsf(v.y) + fabsf(v.z) + fabsf(v.w);
    }
    s = wave_sum(s);
    if ((tid & 63) == 0) sw[tid >> 6] = s;
    __syncthreads();
    if (tid == 0) atomicAdd(&accum[0], sw[0] + sw[1] + sw[2] + sw[3]);
  } else {
    for (int idx = (b - 512) * 256 + tid; idx < 983040; idx += 16384) {
      if (idx < 524288) {            // W1 [1024][512] -> W1T [512][1024]
        int n = idx >> 10, k = idx & 1023;
        W1T[idx] = (bf16_t)W1[k * 512 + n];
      } else if (idx < 655360) {     // W2 [512][256] -> W2T [256][512]
        int i = idx - 524288; int n = i >> 9, k = i & 511;
        W2T[i] = (bf16_t)W2[k * 256 + n];
      } else if (idx < 720896) {     // metric [256][256] -> MT [256][256]
        int i = idx - 655360; int n = i >> 8, k = i & 255;
        MT[i] = (bf16_t)metric[k * 256 + n];
      } else if (idx < 851968) {     // W3 [256][512] -> W3T [512][256]
        int i = idx - 720896; int n = i >> 8, k = i & 255;
        W3T[i] = (bf16_t)W3[k * 512 + n];
      } else {                       // W4 [512][256] -> W4T [256][512]
        int i = idx - 851968; int n = i >> 9, k = i & 511;
        W4T[i] = (bf16_t)W4[k * 256 + n];
      }
    }
  }
}

// -------- normalize rows of mp, emit fp32 (ws + d_out) + bf16, colsums --------
__global__ __launch_bounds__(256) void norm_k(
    float* __restrict__ mpf, float* __restrict__ mp_out,
    bf16_t* __restrict__ mpb, float* __restrict__ colsum) {
  const int tid = threadIdx.x, lane = tid & 63, wid = tid >> 6;
  const int gw = blockIdx.x * 4 + wid, nw = gridDim.x * 4;
  float cs0 = 0.f, cs1 = 0.f, cs2 = 0.f, cs3 = 0.f;
  for (int r = gw; r < NROWS; r += nw) {
    const size_t base = (size_t)r * 256 + lane * 4;
    float4 v = *(const float4*)(mpf + base);
    float s = v.x * v.x + v.y * v.y + v.z * v.z + v.w * v.w;
    s = wave_sum(s);
    const float inv = 1.f / fmaxf(sqrtf(s), 1e-12f);
    v.x *= inv; v.y *= inv; v.z *= inv; v.w *= inv;
    *(float4*)(mpf + base) = v;
    mp_out[base] = v.x; mp_out[base + 1] = v.y;
    mp_out[base + 2] = v.z; mp_out[base + 3] = v.w;
    bf16x4 b;
    b[0] = (bf16_t)v.x; b[1] = (bf16_t)v.y; b[2] = (bf16_t)v.z; b[3] = (bf16_t)v.w;
    *(bf16x4*)(mpb + base) = b;
    cs0 += v.x; cs1 += v.y; cs2 += v.z; cs3 += v.w;
  }
  __shared__ float scs[256];
  scs[tid] = 0.f;
  __syncthreads();
  atomicAdd(&scs[lane * 4 + 0], cs0);
  atomicAdd(&scs[lane * 4 + 1], cs1);
  atomicAdd(&scs[lane * 4 + 2], cs2);
  atomicAdd(&scs[lane * 4 + 3], cs3);
  __syncthreads();
  atomicAdd(&colsum[tid], scs[tid]);
}

// -------- center = colsum/B ; cM = center @ metric --------
__global__ void center_k(const float* __restrict__ colsum,
                         const float* __restrict__ metric,
                         float* __restrict__ center, float* __restrict__ cMv) {
  const int j = threadIdx.x;
  __shared__ float sc[256];
  const float c = colsum[j] * (1.f / 32768.f);
  center[j] = c;
  sc[j] = c;
  __syncthreads();
  float a = 0.f;
  for (int k = 0; k < 256; ++k) a += sc[k] * metric[k * 256 + j];
  cMv[j] = a;
}

// -------- per-row geometry: distances, tangent, gf, stats --------
__global__ __launch_bounds__(256) void geom_k(
    const float* __restrict__ mpf, const float* __restrict__ dm0,
    const float* __restrict__ center, const float* __restrict__ cMv,
    bf16_t* __restrict__ gf, float* __restrict__ accum) {
  const int tid = threadIdx.x, lane = tid & 63, wid = tid >> 6;
  const int gw = blockIdx.x * 4 + wid, nw = gridDim.x * 4;
  const float4 c4 = *(const float4*)(center + lane * 4);
  const float4 q4 = *(const float4*)(cMv + lane * 4);
  float a_d = 0.f, a_d2 = 0.f, a_tn = 0.f;
  for (int r = gw; r < NROWS; r += nw) {
    const size_t base = (size_t)r * 256 + lane * 4;
    float4 m = *(const float4*)(mpf + base);
    float4 d = *(const float4*)(dm0 + base);
    const float dx = m.x - c4.x, dy = m.y - c4.y, dz = m.z - c4.z, dw = m.w - c4.w;
    const float ex = d.x - q4.x, ey = d.y - q4.y, ez = d.z - q4.z, ew = d.w - q4.w;
    float pd = dx * ex + dy * ey + dz * ez + dw * ew;
    float pp = dx * c4.x + dy * c4.y + dz * c4.z + dw * c4.w;
    pd = wave_sum(pd);
    pp = wave_sum(pp);
    const float tx = dx - pp * c4.x, ty = dy - pp * c4.y;
    const float tz = dz - pp * c4.z, tw = dw - pp * c4.w;
    float ptn = tx * tx + ty * ty + tz * tz + tw * tw;
    ptn = wave_sum(ptn);
    bf16x4 g;
    g[0] = (bf16_t)(m.x + 0.1f * tx); g[1] = (bf16_t)(m.y + 0.1f * ty);
    g[2] = (bf16_t)(m.z + 0.1f * tz); g[3] = (bf16_t)(m.w + 0.1f * tw);
    *(bf16x4*)(gf + base) = g;
    if (lane == 0) {
      const float dist = sqrtf(fmaxf(pd, 0.f));
      a_d += dist - 1.f;                    // shifted accumulation (cancellation)
      a_d2 += (dist - 1.f) * (dist - 1.f);
      a_tn += sqrtf(fmaxf(ptn, 0.f));
    }
  }
  __shared__ float sa[3][4];
  if (lane == 0) { sa[0][wid] = a_d; sa[1][wid] = a_d2; sa[2][wid] = a_tn; }
  __syncthreads();
  if (tid == 0) {
    atomicAdd(&accum[1], sa[0][0] + sa[0][1] + sa[0][2] + sa[0][3]);
    atomicAdd(&accum[2], sa[1][0] + sa[1][1] + sa[1][2] + sa[1][3]);
    atomicAdd(&accum[3], sa[2][0] + sa[2][1] + sa[2][2] + sa[2][3]);
  }
}

__global__ void finalize_k(const float* __restrict__ accum, float* __restrict__ out) {
  if (threadIdx.x == 0) {
    const float Bf = 32768.f;
    const float sd = accum[1], sd2 = accum[2], stn = accum[3], cs = accum[0];
    out[8388608] = 1.f + sd / Bf;              // manifold_distance
    out[8388609] = cs * (1.f / 256.f);         // curvature_magnitude
    out[8388610] = stn / Bf;                   // tangent_norm
    const float var = (sd2 - sd * sd / Bf) / (Bf - 1.f);
    out[16777219] = sqrtf(fmaxf(var, 0.f));    // geometric_complexity
  }
}

extern "C" void kernel_launch(void* const* d_in, const int* in_sizes, int n_in,
                              void* d_out, int out_size, void* d_ws, size_t ws_size,
                              hipStream_t stream) {
  const float* x = (const float*)d_in[0];
  const float* W1 = (const float*)d_in[1];
  const float* b1 = (const float*)d_in[2];
  const float* W2 = (const float*)d_in[3];
  const float* b2 = (const float*)d_in[4];
  const float* metric = (const float*)d_in[5];
  const float* conn = (const float*)d_in[6];
  const float* W3 = (const float*)d_in[7];
  const float* b3 = (const float*)d_in[8];
  const float* W4 = (const float*)d_in[9];
  const float* b4 = (const float*)d_in[10];
  float* out_f = (float*)d_out;

  char* ws = (char*)d_ws;
  float* accum = (float*)(ws + 0);          // [0]=conn_sum [1]=sd [2]=sd2 [3]=stn
  float* colsum = (float*)(ws + 256);       // 256 f
  float* center = (float*)(ws + 1280);      // 256 f
  float* cMv = (float*)(ws + 2304);         // 256 f
  bf16_t* W1T = (bf16_t*)(ws + 4096);
  bf16_t* W2T = (bf16_t*)(ws + 1052672);
  bf16_t* MT = (bf16_t*)(ws + 1314816);
  bf16_t* W3T = (bf16_t*)(ws + 1445888);
  bf16_t* W4T = (bf16_t*)(ws + 1708032);
  bf16_t* hB = (bf16_t*)(ws + 2097152);     // 33.5 MB  (later reused as dm0)
  float* dm0 = (float*)(ws + 2097152);
  float* mpf = (float*)(ws + 35651584);     // 33.5 MB  (later reused as g2)
  bf16_t* g2 = (bf16_t*)(ws + 35651584);
  bf16_t* mpb = (bf16_t*)(ws + 69206016);   // 16.8 MB
  bf16_t* gf = (bf16_t*)(ws + 85983232);    // 16.8 MB  (total ~98 MB)

  hipMemsetAsync(d_ws, 0, 4096, stream);
  setup_k<<<576, 256, 0, stream>>>(conn, accum, W1, W1T, W2, W2T, metric, MT,
                                   W3, W3T, W4, W4T);
  // h = relu(x @ W1 + b1)   [32768,512] bf16
  gemm_k<0, true><<<dim3(4, 256), 256, 0, stream>>>(x, W1T, b1, hB, 32768, 512, 1024);
  // mp_raw = h @ W2 + b2    [32768,256] f32
  gemm_k<1, false><<<dim3(2, 256), 256, 0, stream>>>(hB, W2T, b2, mpf, 32768, 256, 512);
  norm_k<<<2048, 256, 0, stream>>>(mpf, out_f + 8388611, mpb, colsum);
  center_k<<<1, 256, 0, stream>>>(colsum, metric, center, cMv);
  // dm0 = mp @ metric       [32768,256] f32   (diff@metric = dm0 - center@metric)
  gemm_k<1, false><<<dim3(2, 256), 256, 0, stream>>>(mpb, MT, nullptr, dm0, 32768, 256, 256);
  geom_k<<<2048, 256, 0, stream>>>(mpf, dm0, center, cMv, gf, accum);
  // g2 = relu(gf @ W3 + b3) [32768,512] bf16
  gemm_k<0, false><<<dim3(4, 256), 256, 0, stream>>>(gf, W3T, b3, g2, 32768, 512, 256);
  // out = g2 @ W4 + b4      [32768,256] f32
  gemm_k<1, false><<<dim3(2, 256), 256, 0, stream>>>(g2, W4T, b4, out_f, 32768, 256, 512);
  finalize_k<<<1, 64, 0, stream>>>(accum, out_f);
}

// Round 3
// 469.801 us; speedup vs baseline: 1.2262x; 1.2262x over previous
//
#include <hip/hip_runtime.h>

typedef __bf16 bf16_t;
typedef __bf16 bf16x8 __attribute__((ext_vector_type(8)));
typedef __bf16 bf16x4 __attribute__((ext_vector_type(4)));
typedef float f32x4 __attribute__((ext_vector_type(4)));

typedef const __attribute__((address_space(1))) void gv_t;
typedef __attribute__((address_space(3))) void lv_t;

#define NROWS 32768

__device__ __forceinline__ float wave_sum(float v) {
#pragma unroll
  for (int o = 32; o > 0; o >>= 1) v += __shfl_xor(v, o, 64);
  return v;
}

// ============ GEMM (N=512): C[M,512] = A[M,K] @ B, relu->bf16 ============
// 128x128 tile, 4 waves. BT [N][K] bf16. CONVA: A fp32, converted in staging.
// 1-D grid of 1024 blocks, bijective XCD swizzle (8 XCDs x 128): the 4
// N-blocks sharing an A-panel land on the same XCD -> A fetched once.
template <bool CONVA>
__global__ __launch_bounds__(256) void gemm_k(
    const void* __restrict__ Ap, const bf16_t* __restrict__ BT,
    const float* __restrict__ bias, bf16_t* __restrict__ Cp, const int K) {
  __shared__ bf16_t sA[128 * 32];
  __shared__ bf16_t sB[128 * 32];
  const int tid = threadIdx.x;
  const int lane = tid & 63;
  const int wid = tid >> 6;
  const int wr = wid >> 1;
  const int wc = wid & 1;
  const int bid = blockIdx.x;
  const int work = ((bid & 7) << 7) + (bid >> 3);  // XCD-contiguous chunks
  const int bm0 = (work >> 2) * 128;               // M-panel (A) shared by
  const int bn0 = (work & 3) * 128;                // 4 consecutive works
  const int N = 512;

  f32x4 acc[4][4];
#pragma unroll
  for (int m = 0; m < 4; ++m)
#pragma unroll
    for (int n = 0; n < 4; ++n) acc[m][n] = f32x4{0.f, 0.f, 0.f, 0.f};

  auto stage = [&](int k0) {
    if constexpr (CONVA) {
      const float* Af = (const float*)Ap;
      const int rb = tid >> 3;
      const int ks = (tid & 7) << 2;
#pragma unroll
      for (int p = 0; p < 4; ++p) {
        const int row = rb + (p << 5);
        const float4 f = *(const float4*)(Af + (size_t)(bm0 + row) * K + k0 + ks);
        bf16x4 w;
        w[0] = (bf16_t)f.x; w[1] = (bf16_t)f.y;
        w[2] = (bf16_t)f.z; w[3] = (bf16_t)f.w;
        *(bf16x4*)(&sA[row * 32 + ks]) = w;
      }
    } else {
      const bf16_t* Ab = (const bf16_t*)Ap;
#pragma unroll
      for (int i = 0; i < 2; ++i) {
        const int off = wid * 2048 + i * 1024;
        const int lidx = off + lane * 16;
        const int row = lidx >> 6;
        const int kb = lidx & 63;
        gv_t* src = (gv_t*)((const char*)(Ab + (size_t)(bm0 + row) * K + k0) + kb);
        __builtin_amdgcn_global_load_lds(src, (lv_t*)((char*)sA + off), 16, 0, 0);
      }
    }
#pragma unroll
    for (int i = 0; i < 2; ++i) {
      const int off = wid * 2048 + i * 1024;
      const int lidx = off + lane * 16;
      const int col = lidx >> 6;
      const int kb = lidx & 63;
      gv_t* src = (gv_t*)((const char*)(BT + (size_t)(bn0 + col) * K + k0) + kb);
      __builtin_amdgcn_global_load_lds(src, (lv_t*)((char*)sB + off), 16, 0, 0);
    }
  };

  stage(0);
  const int arow = lane & 15;
  const int koff = (lane >> 4) * 8;
  for (int k0 = 0;;) {
    __syncthreads();
    bf16x8 af[4], bg[4];
#pragma unroll
    for (int m = 0; m < 4; ++m)
      af[m] = *(const bf16x8*)&sA[(wr * 64 + m * 16 + arow) * 32 + koff];
#pragma unroll
    for (int n = 0; n < 4; ++n)
      bg[n] = *(const bf16x8*)&sB[(wc * 64 + n * 16 + arow) * 32 + koff];
#pragma unroll
    for (int m = 0; m < 4; ++m)
#pragma unroll
      for (int n = 0; n < 4; ++n)
        acc[m][n] = __builtin_amdgcn_mfma_f32_16x16x32_bf16(af[m], bg[n], acc[m][n], 0, 0, 0);
    k0 += 32;
    if (k0 >= K) break;
    __syncthreads();
    stage(k0);
  }

  const int r0 = bm0 + wr * 64 + ((lane >> 4) << 2);
  const int c0 = bn0 + wc * 64 + (lane & 15);
  float bv[4];
#pragma unroll
  for (int n = 0; n < 4; ++n) bv[n] = bias[c0 + n * 16];
#pragma unroll
  for (int m = 0; m < 4; ++m)
#pragma unroll
    for (int n = 0; n < 4; ++n) {
      const size_t base = (size_t)(r0 + m * 16) * N + (c0 + n * 16);
#pragma unroll
      for (int r = 0; r < 4; ++r) {
        float v = acc[m][n][r] + bv[n];
        v = fmaxf(v, 0.f);
        Cp[base + (size_t)r * N] = (bf16_t)v;
      }
    }
}

// ============ Wide GEMM (N=256 full-row tile): 128x256, 8 waves ============
// Each wave owns 16 rows x 256 cols -> row reductions are wave-local.
// EPI 1: acc+bias -> f32 Cp.
// EPI 2: normalize fusion: raw=acc+bias; mp=raw/||raw||; write mp (f32 to
//        mp_out, bf16 to mpb); accumulate colsum.
// EPI 3: geometry fusion: acc = mp@metric; read mp; compute distances,
//        tangent, gf (bf16); accumulate stats into accum[1..3].
template <int EPI>
__global__ __launch_bounds__(512) void wgemm_k(
    const bf16_t* __restrict__ Ap, const bf16_t* __restrict__ BT,
    const float* __restrict__ bias, float* __restrict__ Cp, const int K,
    float* __restrict__ mp_out, bf16_t* __restrict__ mpb,
    float* __restrict__ colsum, const float* __restrict__ center,
    const float* __restrict__ cMv, bf16_t* __restrict__ gf,
    float* __restrict__ accum) {
  __shared__ bf16_t sA[128 * 32];
  __shared__ bf16_t sB[256 * 32];
  const int tid = threadIdx.x;
  const int lane = tid & 63;
  const int wid = tid >> 6;
  const int bm0 = blockIdx.x * 128;

  f32x4 acc[16];
#pragma unroll
  for (int n = 0; n < 16; ++n) acc[n] = f32x4{0.f, 0.f, 0.f, 0.f};

  auto stage = [&](int k0) {
    {  // A: 8 KB, one gload per wave
      const int off = wid * 1024;
      const int lidx = off + lane * 16;
      const int row = lidx >> 6;
      const int kb = lidx & 63;
      gv_t* src = (gv_t*)((const char*)(Ap + (size_t)(bm0 + row) * K + k0) + kb);
      __builtin_amdgcn_global_load_lds(src, (lv_t*)((char*)sA + off), 16, 0, 0);
    }
#pragma unroll
    for (int i = 0; i < 2; ++i) {  // B: 16 KB, two gloads per wave
      const int off = wid * 2048 + i * 1024;
      const int lidx = off + lane * 16;
      const int col = lidx >> 6;
      const int kb = lidx & 63;
      gv_t* src = (gv_t*)((const char*)(BT + (size_t)col * K + k0) + kb);
      __builtin_amdgcn_global_load_lds(src, (lv_t*)((char*)sB + off), 16, 0, 0);
    }
  };

  stage(0);
  const int arow = lane & 15;
  const int koff = (lane >> 4) * 8;
  for (int k0 = 0;;) {
    __syncthreads();
    bf16x8 af = *(const bf16x8*)&sA[(wid * 16 + arow) * 32 + koff];
#pragma unroll
    for (int n = 0; n < 16; ++n) {
      bf16x8 bg = *(const bf16x8*)&sB[(n * 16 + arow) * 32 + koff];
      acc[n] = __builtin_amdgcn_mfma_f32_16x16x32_bf16(af, bg, acc[n], 0, 0, 0);
    }
    k0 += 32;
    if (k0 >= K) break;
    __syncthreads();
    stage(k0);
  }

  const int cl = lane & 15;             // column sub-index
  const int rg = (lane >> 4) << 2;      // row group base (0,4,8,12)

  if constexpr (EPI == 1) {
    float bv[16];
#pragma unroll
    for (int n = 0; n < 16; ++n) bv[n] = bias[n * 16 + cl];
#pragma unroll
    for (int r = 0; r < 4; ++r) {
      const int row = bm0 + wid * 16 + rg + r;
      const size_t rb = (size_t)row * 256 + cl;
#pragma unroll
      for (int n = 0; n < 16; ++n) Cp[rb + n * 16] = acc[n][r] + bv[n];
    }
  }

  if constexpr (EPI == 2) {
    float bv[16], cs[16];
#pragma unroll
    for (int n = 0; n < 16; ++n) { bv[n] = bias[n * 16 + cl]; cs[n] = 0.f; }
#pragma unroll
    for (int r = 0; r < 4; ++r) {
      const int row = bm0 + wid * 16 + rg + r;
      float v[16];
      float ss = 0.f;
#pragma unroll
      for (int n = 0; n < 16; ++n) { v[n] = acc[n][r] + bv[n]; ss += v[n] * v[n]; }
#pragma unroll
      for (int o = 1; o < 16; o <<= 1) ss += __shfl_xor(ss, o, 64);
      const float inv = 1.f / fmaxf(sqrtf(ss), 1e-12f);
      const size_t rb = (size_t)row * 256 + cl;
#pragma unroll
      for (int n = 0; n < 16; ++n) {
        const float m = v[n] * inv;
        mp_out[rb + n * 16] = m;
        mpb[rb + n * 16] = (bf16_t)m;
        cs[n] += m;
      }
    }
#pragma unroll
    for (int n = 0; n < 16; ++n) {
      cs[n] += __shfl_xor(cs[n], 16, 64);
      cs[n] += __shfl_xor(cs[n], 32, 64);
    }
    __shared__ float scs[256];
    if (tid < 256) scs[tid] = 0.f;
    __syncthreads();
    if (lane < 16) {
#pragma unroll
      for (int n = 0; n < 16; ++n) atomicAdd(&scs[n * 16 + lane], cs[n]);
    }
    __syncthreads();
    if (tid < 256) atomicAdd(&colsum[tid], scs[tid]);
  }

  if constexpr (EPI == 3) {
    float c[16], q[16];
#pragma unroll
    for (int n = 0; n < 16; ++n) { c[n] = center[n * 16 + cl]; q[n] = cMv[n * 16 + cl]; }
    float a_d = 0.f, a_d2 = 0.f, a_tn = 0.f;
#pragma unroll
    for (int r = 0; r < 4; ++r) {
      const int row = bm0 + wid * 16 + rg + r;
      const size_t rb = (size_t)row * 256 + cl;
      float mpv[16];
      float pd = 0.f, pp = 0.f;
#pragma unroll
      for (int n = 0; n < 16; ++n) {
        mpv[n] = mp_out[rb + n * 16];
        const float d = mpv[n] - c[n];
        const float e = acc[n][r] - q[n];
        pd += d * e;
        pp += d * c[n];
      }
#pragma unroll
      for (int o = 1; o < 16; o <<= 1) {
        pd += __shfl_xor(pd, o, 64);
        pp += __shfl_xor(pp, o, 64);
      }
      float ptn = 0.f;
#pragma unroll
      for (int n = 0; n < 16; ++n) {
        const float d = mpv[n] - c[n];
        const float t = d - pp * c[n];
        ptn += t * t;
        gf[rb + n * 16] = (bf16_t)(mpv[n] + 0.1f * t);
      }
#pragma unroll
      for (int o = 1; o < 16; o <<= 1) ptn += __shfl_xor(ptn, o, 64);
      if (cl == 0) {
        const float dist = sqrtf(fmaxf(pd, 0.f));
        a_d += dist - 1.f;                     // shifted accumulation
        a_d2 += (dist - 1.f) * (dist - 1.f);
        a_tn += sqrtf(fmaxf(ptn, 0.f));
      }
    }
    a_d += __shfl_xor(a_d, 16, 64);  a_d += __shfl_xor(a_d, 32, 64);
    a_d2 += __shfl_xor(a_d2, 16, 64); a_d2 += __shfl_xor(a_d2, 32, 64);
    a_tn += __shfl_xor(a_tn, 16, 64); a_tn += __shfl_xor(a_tn, 32, 64);
    __shared__ float sa[3][8];
    if (lane == 0) { sa[0][wid] = a_d; sa[1][wid] = a_d2; sa[2][wid] = a_tn; }
    __syncthreads();
    if (tid == 0) {
      float s0 = 0.f, s1 = 0.f, s2 = 0.f;
#pragma unroll
      for (int w = 0; w < 8; ++w) { s0 += sa[0][w]; s1 += sa[1][w]; s2 += sa[2][w]; }
      atomicAdd(&accum[1], s0);
      atomicAdd(&accum[2], s1);
      atomicAdd(&accum[3], s2);
    }
  }
}

// -------- setup: conn abs-sum + weight transpose/convert to bf16 --------
__global__ __launch_bounds__(256) void setup_k(
    const float* __restrict__ conn, float* __restrict__ accum,
    const float* __restrict__ W1, bf16_t* __restrict__ W1T,
    const float* __restrict__ W2, bf16_t* __restrict__ W2T,
    const float* __restrict__ metric, bf16_t* __restrict__ MT,
    const float* __restrict__ W3, bf16_t* __restrict__ W3T,
    const float* __restrict__ W4, bf16_t* __restrict__ W4T) {
  const int b = blockIdx.x, tid = threadIdx.x;
  __shared__ float sw[4];
  if (b < 512) {
    const float4* src = (const float4*)conn + (size_t)b * 8192;
    float s = 0.f;
    for (int i = tid; i < 8192; i += 256) {
      float4 v = src[i];
      s += fabsf(v.x) + fabsf(v.y) + fabsf(v.z) + fabsf(v.w);
    }
    s = wave_sum(s);
    if ((tid & 63) == 0) sw[tid >> 6] = s;
    __syncthreads();
    if (tid == 0) atomicAdd(&accum[0], sw[0] + sw[1] + sw[2] + sw[3]);
  } else {
    for (int idx = (b - 512) * 256 + tid; idx < 983040; idx += 16384) {
      if (idx < 524288) {            // W1 [1024][512] -> W1T [512][1024]
        int n = idx >> 10, k = idx & 1023;
        W1T[idx] = (bf16_t)W1[k * 512 + n];
      } else if (idx < 655360) {     // W2 [512][256] -> W2T [256][512]
        int i = idx - 524288; int n = i >> 9, k = i & 511;
        W2T[i] = (bf16_t)W2[k * 256 + n];
      } else if (idx < 720896) {     // metric [256][256] -> MT
        int i = idx - 655360; int n = i >> 8, k = i & 255;
        MT[i] = (bf16_t)metric[k * 256 + n];
      } else if (idx < 851968) {     // W3 [256][512] -> W3T [512][256]
        int i = idx - 720896; int n = i >> 8, k = i & 255;
        W3T[i] = (bf16_t)W3[k * 512 + n];
      } else {                       // W4 [512][256] -> W4T [256][512]
        int i = idx - 851968; int n = i >> 9, k = i & 511;
        W4T[i] = (bf16_t)W4[k * 256 + n];
      }
    }
  }
}

// -------- center = colsum/B ; cM = center @ metric --------
__global__ void center_k(const float* __restrict__ colsum,
                         const float* __restrict__ metric,
                         float* __restrict__ center, float* __restrict__ cMv) {
  const int j = threadIdx.x;
  __shared__ float sc[256];
  const float c = colsum[j] * (1.f / 32768.f);
  center[j] = c;
  sc[j] = c;
  __syncthreads();
  float a = 0.f;
  for (int k = 0; k < 256; ++k) a += sc[k] * metric[k * 256 + j];
  cMv[j] = a;
}

__global__ void finalize_k(const float* __restrict__ accum, float* __restrict__ out) {
  if (threadIdx.x == 0) {
    const float Bf = 32768.f;
    const float sd = accum[1], sd2 = accum[2], stn = accum[3], cs = accum[0];
    out[8388608] = 1.f + sd / Bf;              // manifold_distance
    out[8388609] = cs * (1.f / 256.f);         // curvature_magnitude
    out[8388610] = stn / Bf;                   // tangent_norm
    const float var = (sd2 - sd * sd / Bf) / (Bf - 1.f);
    out[16777219] = sqrtf(fmaxf(var, 0.f));    // geometric_complexity
  }
}

extern "C" void kernel_launch(void* const* d_in, const int* in_sizes, int n_in,
                              void* d_out, int out_size, void* d_ws, size_t ws_size,
                              hipStream_t stream) {
  const float* x = (const float*)d_in[0];
  const float* W1 = (const float*)d_in[1];
  const float* b1 = (const float*)d_in[2];
  const float* W2 = (const float*)d_in[3];
  const float* b2 = (const float*)d_in[4];
  const float* metric = (const float*)d_in[5];
  const float* conn = (const float*)d_in[6];
  const float* W3 = (const float*)d_in[7];
  const float* b3 = (const float*)d_in[8];
  const float* W4 = (const float*)d_in[9];
  const float* b4 = (const float*)d_in[10];
  float* out_f = (float*)d_out;
  float* mp_out = out_f + 8388611;  // normalized mp lives in d_out directly

  char* ws = (char*)d_ws;
  float* accum = (float*)(ws + 0);          // [0]=conn_sum [1]=sd [2]=sd2 [3]=stn
  float* colsum = (float*)(ws + 256);
  float* center = (float*)(ws + 1280);
  float* cMv = (float*)(ws + 2304);
  bf16_t* W1T = (bf16_t*)(ws + 4096);
  bf16_t* W2T = (bf16_t*)(ws + 1052672);
  bf16_t* MT = (bf16_t*)(ws + 1314816);
  bf16_t* W3T = (bf16_t*)(ws + 1445888);
  bf16_t* W4T = (bf16_t*)(ws + 1708032);
  bf16_t* hB = (bf16_t*)(ws + 2097152);     // 33.5 MB
  bf16_t* g2 = (bf16_t*)(ws + 35651584);    // 33.5 MB
  bf16_t* mpb = (bf16_t*)(ws + 69206016);   // 16.8 MB
  bf16_t* gf = (bf16_t*)(ws + 85983232);    // 16.8 MB

  hipMemsetAsync(d_ws, 0, 4096, stream);
  setup_k<<<576, 256, 0, stream>>>(conn, accum, W1, W1T, W2, W2T, metric, MT,
                                   W3, W3T, W4, W4T);
  // h = relu(x @ W1 + b1)   [32768,512] bf16   (A fp32 converted in-staging)
  gemm_k<true><<<1024, 256, 0, stream>>>(x, W1T, b1, hB, 1024);
  // mp = normalize(h @ W2 + b2)  -> mp_out(f32) + mpb(bf16) + colsum
  wgemm_k<2><<<256, 512, 0, stream>>>(hB, W2T, b2, nullptr, 512, mp_out, mpb,
                                      colsum, nullptr, nullptr, nullptr, nullptr);
  center_k<<<1, 256, 0, stream>>>(colsum, metric, center, cMv);
  // acc = mp @ metric ; fused distances/tangent/gf/stats
  wgemm_k<3><<<256, 512, 0, stream>>>(mpb, MT, nullptr, nullptr, 256, mp_out,
                                      nullptr, nullptr, center, cMv, gf, accum);
  // g2 = relu(gf @ W3 + b3) [32768,512] bf16
  gemm_k<false><<<1024, 256, 0, stream>>>(gf, W3T, b3, g2, 256);
  // out = g2 @ W4 + b4      [32768,256] f32 -> d_out
  wgemm_k<1><<<256, 512, 0, stream>>>(g2, W4T, b4, out_f, 512, nullptr, nullptr,
                                      nullptr, nullptr, nullptr, nullptr, nullptr);
  finalize_k<<<1, 64, 0, stream>>>(accum, out_f);
}

// Round 4
// 456.431 us; speedup vs baseline: 1.2621x; 1.0293x over previous
//
#include <hip/hip_runtime.h>

typedef __bf16 bf16_t;
typedef __bf16 bf16x8 __attribute__((ext_vector_type(8)));
typedef __bf16 bf16x4 __attribute__((ext_vector_type(4)));
typedef float f32x4 __attribute__((ext_vector_type(4)));

typedef const __attribute__((address_space(1))) void gv_t;
typedef __attribute__((address_space(3))) void lv_t;

#define NROWS 32768

__device__ __forceinline__ float wave_sum(float v) {
#pragma unroll
  for (int o = 32; o > 0; o >>= 1) v += __shfl_xor(v, o, 64);
  return v;
}

// ============ GEMM (N=512): C[M,512] = A[M,K] @ B, relu->bf16 ============
// 128x128 tile, 4 waves, double-buffered 2-phase: stage(t+1) issued BEFORE
// ds_read+MFMA of t, ONE barrier per K-step (vmcnt(0) drain at barrier covers
// next-tile loads; lgkm drain covers current reads -> WAR safe).
// Grid 1024, bijective XCD swizzle: 4 N-blocks of an M-panel on one XCD.
__global__ __launch_bounds__(256) void gemm_k(
    const bf16_t* __restrict__ Ap, const bf16_t* __restrict__ BT,
    const float* __restrict__ bias, bf16_t* __restrict__ Cp, const int K) {
  __shared__ bf16_t sA[2][128 * 32];
  __shared__ bf16_t sB[2][128 * 32];
  const int tid = threadIdx.x;
  const int lane = tid & 63;
  const int wid = tid >> 6;
  const int wr = wid >> 1;
  const int wc = wid & 1;
  const int bid = blockIdx.x;
  const int work = ((bid & 7) << 7) + (bid >> 3);  // XCD-contiguous chunks
  const int bm0 = (work >> 2) * 128;
  const int bn0 = (work & 3) * 128;
  const int N = 512;

  f32x4 acc[4][4];
#pragma unroll
  for (int m = 0; m < 4; ++m)
#pragma unroll
    for (int n = 0; n < 4; ++n) acc[m][n] = f32x4{0.f, 0.f, 0.f, 0.f};

  auto stage = [&](bf16_t* dA, bf16_t* dB, int k0) {
#pragma unroll
    for (int i = 0; i < 2; ++i) {
      const int off = wid * 2048 + i * 1024;
      const int lidx = off + lane * 16;
      const int row = lidx >> 6;  // 64 B per 32-elem bf16 row
      const int kb = lidx & 63;
      gv_t* srcA = (gv_t*)((const char*)(Ap + (size_t)(bm0 + row) * K + k0) + kb);
      __builtin_amdgcn_global_load_lds(srcA, (lv_t*)((char*)dA + off), 16, 0, 0);
      gv_t* srcB = (gv_t*)((const char*)(BT + (size_t)(bn0 + row) * K + k0) + kb);
      __builtin_amdgcn_global_load_lds(srcB, (lv_t*)((char*)dB + off), 16, 0, 0);
    }
  };

  stage(sA[0], sB[0], 0);
  const int arow = lane & 15;
  const int koff = (lane >> 4) * 8;
  const int nt = K >> 5;
  int cur = 0;
  __syncthreads();
  for (int t = 0; t < nt; ++t) {
    if (t + 1 < nt) stage(sA[cur ^ 1], sB[cur ^ 1], (t + 1) << 5);
    bf16x8 af[4], bg[4];
#pragma unroll
    for (int m = 0; m < 4; ++m)
      af[m] = *(const bf16x8*)&sA[cur][(wr * 64 + m * 16 + arow) * 32 + koff];
#pragma unroll
    for (int n = 0; n < 4; ++n)
      bg[n] = *(const bf16x8*)&sB[cur][(wc * 64 + n * 16 + arow) * 32 + koff];
#pragma unroll
    for (int m = 0; m < 4; ++m)
#pragma unroll
      for (int n = 0; n < 4; ++n)
        acc[m][n] = __builtin_amdgcn_mfma_f32_16x16x32_bf16(af[m], bg[n], acc[m][n], 0, 0, 0);
    __syncthreads();
    cur ^= 1;
  }

  const int r0 = bm0 + wr * 64 + ((lane >> 4) << 2);
  const int c0 = bn0 + wc * 64 + (lane & 15);
  float bv[4];
#pragma unroll
  for (int n = 0; n < 4; ++n) bv[n] = bias[c0 + n * 16];
#pragma unroll
  for (int m = 0; m < 4; ++m)
#pragma unroll
    for (int n = 0; n < 4; ++n) {
      const size_t base = (size_t)(r0 + m * 16) * N + (c0 + n * 16);
#pragma unroll
      for (int r = 0; r < 4; ++r) {
        float v = acc[m][n][r] + bv[n];
        v = fmaxf(v, 0.f);
        Cp[base + (size_t)r * N] = (bf16_t)v;
      }
    }
}

// ============ Wide GEMM (N=256 full-row tile): 128x256, 8 waves ============
// Double-buffered 2-phase like gemm_k. Wave owns 16 rows x 256 cols.
// EPI 1: acc+bias -> f32. EPI 2: normalize fusion. EPI 3: geometry fusion.
template <int EPI>
__global__ __launch_bounds__(512) void wgemm_k(
    const bf16_t* __restrict__ Ap, const bf16_t* __restrict__ BT,
    const float* __restrict__ bias, float* __restrict__ Cp, const int K,
    float* __restrict__ mp_out, bf16_t* __restrict__ mpb,
    float* __restrict__ colsum, const float* __restrict__ center,
    const float* __restrict__ cMv, bf16_t* __restrict__ gf,
    float* __restrict__ accum) {
  __shared__ bf16_t sA[2][128 * 32];
  __shared__ bf16_t sB[2][256 * 32];
  const int tid = threadIdx.x;
  const int lane = tid & 63;
  const int wid = tid >> 6;
  const int bm0 = blockIdx.x * 128;

  f32x4 acc[16];
#pragma unroll
  for (int n = 0; n < 16; ++n) acc[n] = f32x4{0.f, 0.f, 0.f, 0.f};

  auto stage = [&](bf16_t* dA, bf16_t* dB, int k0) {
    {
      const int off = wid * 1024;
      const int lidx = off + lane * 16;
      const int row = lidx >> 6;
      const int kb = lidx & 63;
      gv_t* src = (gv_t*)((const char*)(Ap + (size_t)(bm0 + row) * K + k0) + kb);
      __builtin_amdgcn_global_load_lds(src, (lv_t*)((char*)dA + off), 16, 0, 0);
    }
#pragma unroll
    for (int i = 0; i < 2; ++i) {
      const int off = wid * 2048 + i * 1024;
      const int lidx = off + lane * 16;
      const int col = lidx >> 6;
      const int kb = lidx & 63;
      gv_t* src = (gv_t*)((const char*)(BT + (size_t)col * K + k0) + kb);
      __builtin_amdgcn_global_load_lds(src, (lv_t*)((char*)dB + off), 16, 0, 0);
    }
  };

  stage(sA[0], sB[0], 0);
  const int arow = lane & 15;
  const int koff = (lane >> 4) * 8;
  const int nt = K >> 5;
  int cur = 0;
  __syncthreads();
  for (int t = 0; t < nt; ++t) {
    if (t + 1 < nt) stage(sA[cur ^ 1], sB[cur ^ 1], (t + 1) << 5);
    bf16x8 af = *(const bf16x8*)&sA[cur][(wid * 16 + arow) * 32 + koff];
#pragma unroll
    for (int n = 0; n < 16; ++n) {
      bf16x8 bg = *(const bf16x8*)&sB[cur][(n * 16 + arow) * 32 + koff];
      acc[n] = __builtin_amdgcn_mfma_f32_16x16x32_bf16(af, bg, acc[n], 0, 0, 0);
    }
    __syncthreads();
    cur ^= 1;
  }

  const int cl = lane & 15;
  const int rg = (lane >> 4) << 2;

  if constexpr (EPI == 1) {
    float bv[16];
#pragma unroll
    for (int n = 0; n < 16; ++n) bv[n] = bias[n * 16 + cl];
#pragma unroll
    for (int r = 0; r < 4; ++r) {
      const int row = bm0 + wid * 16 + rg + r;
      const size_t rb = (size_t)row * 256 + cl;
#pragma unroll
      for (int n = 0; n < 16; ++n) Cp[rb + n * 16] = acc[n][r] + bv[n];
    }
  }

  if constexpr (EPI == 2) {
    float bv[16], cs[16];
#pragma unroll
    for (int n = 0; n < 16; ++n) { bv[n] = bias[n * 16 + cl]; cs[n] = 0.f; }
#pragma unroll
    for (int r = 0; r < 4; ++r) {
      const int row = bm0 + wid * 16 + rg + r;
      float v[16];
      float ss = 0.f;
#pragma unroll
      for (int n = 0; n < 16; ++n) { v[n] = acc[n][r] + bv[n]; ss += v[n] * v[n]; }
#pragma unroll
      for (int o = 1; o < 16; o <<= 1) ss += __shfl_xor(ss, o, 64);
      const float inv = 1.f / fmaxf(sqrtf(ss), 1e-12f);
      const size_t rb = (size_t)row * 256 + cl;
#pragma unroll
      for (int n = 0; n < 16; ++n) {
        const float m = v[n] * inv;
        mp_out[rb + n * 16] = m;
        mpb[rb + n * 16] = (bf16_t)m;
        cs[n] += m;
      }
    }
#pragma unroll
    for (int n = 0; n < 16; ++n) {
      cs[n] += __shfl_xor(cs[n], 16, 64);
      cs[n] += __shfl_xor(cs[n], 32, 64);
    }
    __shared__ float scs[256];
    if (tid < 256) scs[tid] = 0.f;
    __syncthreads();
    if (lane < 16) {
#pragma unroll
      for (int n = 0; n < 16; ++n) atomicAdd(&scs[n * 16 + lane], cs[n]);
    }
    __syncthreads();
    if (tid < 256) atomicAdd(&colsum[tid], scs[tid]);
  }

  if constexpr (EPI == 3) {
    float c[16], q[16];
#pragma unroll
    for (int n = 0; n < 16; ++n) { c[n] = center[n * 16 + cl]; q[n] = cMv[n * 16 + cl]; }
    float a_d = 0.f, a_d2 = 0.f, a_tn = 0.f;
#pragma unroll
    for (int r = 0; r < 4; ++r) {
      const int row = bm0 + wid * 16 + rg + r;
      const size_t rb = (size_t)row * 256 + cl;
      float mpv[16];
      float pd = 0.f, pp = 0.f;
#pragma unroll
      for (int n = 0; n < 16; ++n) {
        mpv[n] = mp_out[rb + n * 16];
        const float d = mpv[n] - c[n];
        const float e = acc[n][r] - q[n];
        pd += d * e;
        pp += d * c[n];
      }
#pragma unroll
      for (int o = 1; o < 16; o <<= 1) {
        pd += __shfl_xor(pd, o, 64);
        pp += __shfl_xor(pp, o, 64);
      }
      float ptn = 0.f;
#pragma unroll
      for (int n = 0; n < 16; ++n) {
        const float d = mpv[n] - c[n];
        const float t = d - pp * c[n];
        ptn += t * t;
        gf[rb + n * 16] = (bf16_t)(mpv[n] + 0.1f * t);
      }
#pragma unroll
      for (int o = 1; o < 16; o <<= 1) ptn += __shfl_xor(ptn, o, 64);
      if (cl == 0) {
        const float dist = sqrtf(fmaxf(pd, 0.f));
        a_d += dist - 1.f;                     // shifted accumulation
        a_d2 += (dist - 1.f) * (dist - 1.f);
        a_tn += sqrtf(fmaxf(ptn, 0.f));
      }
    }
    a_d += __shfl_xor(a_d, 16, 64);  a_d += __shfl_xor(a_d, 32, 64);
    a_d2 += __shfl_xor(a_d2, 16, 64); a_d2 += __shfl_xor(a_d2, 32, 64);
    a_tn += __shfl_xor(a_tn, 16, 64); a_tn += __shfl_xor(a_tn, 32, 64);
    __shared__ float sa[3][8];
    if (lane == 0) { sa[0][wid] = a_d; sa[1][wid] = a_d2; sa[2][wid] = a_tn; }
    __syncthreads();
    if (tid == 0) {
      float s0 = 0.f, s1 = 0.f, s2 = 0.f;
#pragma unroll
      for (int w = 0; w < 8; ++w) { s0 += sa[0][w]; s1 += sa[1][w]; s2 += sa[2][w]; }
      atomicAdd(&accum[1], s0);
      atomicAdd(&accum[2], s1);
      atomicAdd(&accum[3], s2);
    }
  }
}

// -- setup: conn abs-sum + weight transpose->bf16 + x->bf16 convert --
__global__ __launch_bounds__(256) void setup_k(
    const float* __restrict__ conn, float* __restrict__ accum,
    const float* __restrict__ W1, bf16_t* __restrict__ W1T,
    const float* __restrict__ W2, bf16_t* __restrict__ W2T,
    const float* __restrict__ metric, bf16_t* __restrict__ MT,
    const float* __restrict__ W3, bf16_t* __restrict__ W3T,
    const float* __restrict__ W4, bf16_t* __restrict__ W4T,
    const float* __restrict__ x, bf16_t* __restrict__ xb) {
  const int b = blockIdx.x, tid = threadIdx.x;
  __shared__ float sw[4];
  if (b < 512) {
    const float4* src = (const float4*)conn + (size_t)b * 8192;
    float s = 0.f;
    for (int i = tid; i < 8192; i += 256) {
      float4 v = src[i];
      s += fabsf(v.x) + fabsf(v.y) + fabsf(v.z) + fabsf(v.w);
    }
    s = wave_sum(s);
    if ((tid & 63) == 0) sw[tid >> 6] = s;
    __syncthreads();
    if (tid == 0) atomicAdd(&accum[0], sw[0] + sw[1] + sw[2] + sw[3]);
  } else if (b < 576) {
    for (int idx = (b - 512) * 256 + tid; idx < 983040; idx += 16384) {
      if (idx < 524288) {            // W1 [1024][512] -> W1T [512][1024]
        int n = idx >> 10, k = idx & 1023;
        W1T[idx] = (bf16_t)W1[k * 512 + n];
      } else if (idx < 655360) {     // W2 [512][256] -> W2T [256][512]
        int i = idx - 524288; int n = i >> 9, k = i & 511;
        W2T[i] = (bf16_t)W2[k * 256 + n];
      } else if (idx < 720896) {     // metric [256][256] -> MT
        int i = idx - 655360; int n = i >> 8, k = i & 255;
        MT[i] = (bf16_t)metric[k * 256 + n];
      } else if (idx < 851968) {     // W3 [256][512] -> W3T [512][256]
        int i = idx - 720896; int n = i >> 8, k = i & 255;
        W3T[i] = (bf16_t)W3[k * 512 + n];
      } else {                       // W4 [512][256] -> W4T [256][512]
        int i = idx - 851968; int n = i >> 9, k = i & 511;
        W4T[i] = (bf16_t)W4[k * 256 + n];
      }
    }
  } else {  // x fp32 -> bf16, 512 blocks, vectorized
    const float4* xs = (const float4*)x;
    bf16x4* xd = (bf16x4*)xb;
    for (int i = (b - 576) * 256 + tid; i < 8388608; i += 131072) {
      const float4 v = xs[i];
      bf16x4 w;
      w[0] = (bf16_t)v.x; w[1] = (bf16_t)v.y;
      w[2] = (bf16_t)v.z; w[3] = (bf16_t)v.w;
      xd[i] = w;
    }
  }
}

// -------- center = colsum/B ; cM = center @ metric --------
__global__ void center_k(const float* __restrict__ colsum,
                         const float* __restrict__ metric,
                         float* __restrict__ center, float* __restrict__ cMv) {
  const int j = threadIdx.x;
  __shared__ float sc[256];
  const float c = colsum[j] * (1.f / 32768.f);
  center[j] = c;
  sc[j] = c;
  __syncthreads();
  float a = 0.f;
  for (int k = 0; k < 256; ++k) a += sc[k] * metric[k * 256 + j];
  cMv[j] = a;
}

__global__ void finalize_k(const float* __restrict__ accum, float* __restrict__ out) {
  if (threadIdx.x == 0) {
    const float Bf = 32768.f;
    const float sd = accum[1], sd2 = accum[2], stn = accum[3], cs = accum[0];
    out[8388608] = 1.f + sd / Bf;              // manifold_distance
    out[8388609] = cs * (1.f / 256.f);         // curvature_magnitude
    out[8388610] = stn / Bf;                   // tangent_norm
    const float var = (sd2 - sd * sd / Bf) / (Bf - 1.f);
    out[16777219] = sqrtf(fmaxf(var, 0.f));    // geometric_complexity
  }
}

extern "C" void kernel_launch(void* const* d_in, const int* in_sizes, int n_in,
                              void* d_out, int out_size, void* d_ws, size_t ws_size,
                              hipStream_t stream) {
  const float* x = (const float*)d_in[0];
  const float* W1 = (const float*)d_in[1];
  const float* b1 = (const float*)d_in[2];
  const float* W2 = (const float*)d_in[3];
  const float* b2 = (const float*)d_in[4];
  const float* metric = (const float*)d_in[5];
  const float* conn = (const float*)d_in[6];
  const float* W3 = (const float*)d_in[7];
  const float* b3 = (const float*)d_in[8];
  const float* W4 = (const float*)d_in[9];
  const float* b4 = (const float*)d_in[10];
  float* out_f = (float*)d_out;
  float* mp_out = out_f + 8388611;  // normalized mp lives in d_out directly

  char* ws = (char*)d_ws;
  float* accum = (float*)(ws + 0);          // [0]=conn_sum [1]=sd [2]=sd2 [3]=stn
  float* colsum = (float*)(ws + 256);
  float* center = (float*)(ws + 1280);
  float* cMv = (float*)(ws + 2304);
  bf16_t* W1T = (bf16_t*)(ws + 4096);
  bf16_t* W2T = (bf16_t*)(ws + 1052672);
  bf16_t* MT = (bf16_t*)(ws + 1314816);
  bf16_t* W3T = (bf16_t*)(ws + 1445888);
  bf16_t* W4T = (bf16_t*)(ws + 1708032);
  bf16_t* hB = (bf16_t*)(ws + 2097152);     // 33.5 MB
  // xb (67.1 MB) aliases [g2|mpb|gf]: xb is dead after gemm1; g2/mpb/gf are
  // written only after gemm1 completes. Keeps ws at ~98 MB.
  bf16_t* xb = (bf16_t*)(ws + 35651584);
  bf16_t* g2 = (bf16_t*)(ws + 35651584);    // 33.5 MB
  bf16_t* mpb = (bf16_t*)(ws + 69206016);   // 16.8 MB
  bf16_t* gf = (bf16_t*)(ws + 85983232);    // 16.8 MB (ends 102760448)

  hipMemsetAsync(d_ws, 0, 4096, stream);
  setup_k<<<1088, 256, 0, stream>>>(conn, accum, W1, W1T, W2, W2T, metric, MT,
                                    W3, W3T, W4, W4T, x, xb);
  // h = relu(x @ W1 + b1)   [32768,512] bf16
  gemm_k<<<1024, 256, 0, stream>>>(xb, W1T, b1, hB, 1024);
  // mp = normalize(h @ W2 + b2)  -> mp_out(f32) + mpb(bf16) + colsum
  wgemm_k<2><<<256, 512, 0, stream>>>(hB, W2T, b2, nullptr, 512, mp_out, mpb,
                                      colsum, nullptr, nullptr, nullptr, nullptr);
  center_k<<<1, 256, 0, stream>>>(colsum, metric, center, cMv);
  // acc = mp @ metric ; fused distances/tangent/gf/stats
  wgemm_k<3><<<256, 512, 0, stream>>>(mpb, MT, nullptr, nullptr, 256, mp_out,
                                      nullptr, nullptr, center, cMv, gf, accum);
  // g2 = relu(gf @ W3 + b3) [32768,512] bf16
  gemm_k<<<1024, 256, 0, stream>>>(gf, W3T, b3, g2, 256);
  // out = g2 @ W4 + b4      [32768,256] f32 -> d_out
  wgemm_k<1><<<256, 512, 0, stream>>>(g2, W4T, b4, out_f, 512, nullptr, nullptr,
                                      nullptr, nullptr, nullptr, nullptr, nullptr);
  finalize_k<<<1, 64, 0, stream>>>(accum, out_f);
}